// Round 12
// baseline (538.605 us; speedup 1.0000x reference)
//
#include <hip/hip_runtime.h>
#include <hip/hip_fp16.h>
#include <math.h>

#define NLVL 16
#define TSIZE 16384
#define BLK 1024
#define PPT 2                 // points per thread
#define PPB (BLK * PPT)       // points per block

typedef float floatx4 __attribute__((ext_vector_type(4)));

struct NsArg { float nf[NLVL]; };

// ---- pre-pass: f32 table -> f16 (values |v|<=1e-4 -> abs err <=5e-8) ----
__global__ __launch_bounds__(256) void cvt_tbl(
    const float2* __restrict__ src, __half2* __restrict__ dst, int n)
{
    int i = blockIdx.x * 256 + threadIdx.x;
    if (i < n) { float2 v = src[i]; dst[i] = __floats2half2_rn(v.x, v.y); }
}

// One trilinear gather for point p at level Nf from LDS buffer at byte
// offset BUF. Hash operands pre-shifted by 2 ((x^y)<<2 == (x<<2)^(y<<2)),
// buffer select folded into and-or. acc in f32.
#define CORNER(E, CK, W, BUF) { \
    unsigned off = ((((E)^(CK)) & 0xFFFCu) | (BUF)); \
    __half2 g = *(const __half2*)((const char*)sh + off); \
    float2 gf = __half22float2(g); float w = (W); \
    acc0 = fmaf(w, gf.x, acc0); acc1 = fmaf(w, gf.y, acc1); }

#define GATHER(p, lc, BUF) { \
    float t0 = X0[p]*Nf, t1 = X1[p]*Nf, t2 = X2[p]*Nf; \
    float fl0 = floorf(t0), fl1 = floorf(t1), fl2 = floorf(t2); \
    float p0 = t0-fl0, p1 = t1-fl1, p2 = t2-fl2; \
    unsigned A0 = ((unsigned)fl0) << 2, A1 = A0 + 4u; \
    unsigned B0 = ((unsigned)fl1) * P1s, B1 = B0 + P1s; \
    unsigned C0 = ((unsigned)fl2) * P2s, C1 = C0 + P2s; \
    unsigned e00 = A0^B0, e01 = A0^B1, e10 = A1^B0, e11 = A1^B1; \
    float q0 = 1.f-p0, q1 = 1.f-p1, q2 = 1.f-p2; \
    float w00 = q0*q1, w01 = q0*p1, w10 = p0*q1, w11 = p0*p1; \
    float acc0 = 0.f, acc1 = 0.f; \
    CORNER(e00, C0, w00*q2, BUF) CORNER(e00, C1, w00*p2, BUF) \
    CORNER(e01, C0, w01*q2, BUF) CORNER(e01, C1, w01*p2, BUF) \
    CORNER(e10, C0, w10*q2, BUF) CORNER(e10, C1, w10*p2, BUF) \
    CORNER(e11, C0, w11*q2, BUF) CORNER(e11, C1, w11*p2, BUF) \
    res[p][2*(lc)]   = acc0; \
    res[p][2*(lc)+1] = acc1; }

// Software-pipelined dbuf, REGISTER staging (global_load_lds banned: R7/R10
// showed +0.7GB HBM). Per level: load half of next level's 64KB -> gather
// p0 (covers L2 latency) -> ds_write + load other half -> gather p1 ->
// write -> ONE barrier. Outer c loop runtime so code stays compact and res
// indexing static (R3 lesson: full unroll => hoisted loads => spill).
__global__ __launch_bounds__(BLK) void hashgrid_pipe(
    const float* __restrict__ inp,
    const __half2* __restrict__ tbl,   // f16 table in d_ws
    float* __restrict__ out,
    NsArg ns, int npts)
{
    __shared__ __align__(16) __half2 sh[2][TSIZE];   // 2 x 64 KiB
    const unsigned P1s = 2654435761u * 4u, P2s = 805459861u * 4u;
    const int tid  = threadIdx.x;
    const int base = blockIdx.x * PPB;

    float X0[PPT], X1[PPT], X2[PPT];
#pragma unroll
    for (int p = 0; p < PPT; ++p) {
        int n = base + tid + p * BLK;
        int m = n < npts ? n : 0;
        X0[p] = (inp[3*m+0] + 3.0f) / 6.0f;
        X1[p] = (inp[3*m+1] + 3.0f) / 6.0f;
        X2[p] = (inp[3*m+2] + 3.0f) / 6.0f;
    }

    // Prologue: stage level 0 into sh[0] (register path, unroll 2).
    {
        const floatx4* src = (const floatx4*)tbl;
        floatx4* dst = (floatx4*)&sh[0][0];
#pragma unroll 2
        for (int k = 0; k < 4; ++k)
            dst[tid + k*BLK] = src[tid + k*BLK];
    }
    __syncthreads();

    for (int c = 0; c < NLVL/4; ++c) {     // runtime: 4 chunks
        float res[PPT][8];                 // static-indexed, 16 floats

#pragma unroll
        for (int lc = 0; lc < 4; ++lc) {
            const unsigned BUF  = (lc & 1) ? 65536u : 0u;      // compile-time
            const int lvl = c*4 + lc;
            const bool do_stage = (lc < 3) || (c < 3);         // lvl+1 < 16
            const floatx4* src = (const floatx4*)(tbl + (lvl+1) * TSIZE);
            floatx4* dst = (floatx4*)((char*)sh + (((lc+1)&1) << 16));
            const float Nf = ns.nf[lvl];

            floatx4 s0, s1;
            if (do_stage) { s0 = src[tid]; s1 = src[tid + BLK]; }

            GATHER(0, lc, BUF)             // covers staging-load latency

            if (do_stage) {
                dst[tid] = s0; dst[tid + BLK] = s1;
                s0 = src[tid + 2*BLK]; s1 = src[tid + 3*BLK];
            }

            GATHER(1, lc, BUF)

            if (do_stage) { dst[tid + 2*BLK] = s0; dst[tid + 3*BLK] = s1; }

            __syncthreads();   // one barrier/level: next level staged, cur free
        }

        // ---- store chunk c: 2 float4 per point (proven clean traffic) ----
#pragma unroll
        for (int p = 0; p < PPT; ++p) {
            int n = base + tid + p * BLK;
            if (n < npts) {
                floatx4* o = (floatx4*)(out + (size_t)n * (2*NLVL) + c * 8);
                const floatx4* r = (const floatx4*)res[p];
                o[0] = r[0];
                o[1] = r[1];
            }
        }
    }
}

// ---- fallback (f32 direct global gathers) if ws too small ----
__global__ __launch_bounds__(256) void hashgrid_glb(
    const float* __restrict__ inp,
    const float2* __restrict__ tbl,
    float* __restrict__ out,
    NsArg ns, int npts)
{
    int n = blockIdx.x * 256 + threadIdx.x;
    if (n >= npts) return;
    const unsigned P1 = 2654435761u, P2 = 805459861u;
    float x0 = (inp[3*n+0] + 3.0f) / 6.0f;
    float x1 = (inp[3*n+1] + 3.0f) / 6.0f;
    float x2 = (inp[3*n+2] + 3.0f) / 6.0f;
    float res[2*NLVL];
#pragma unroll
    for (int l = 0; l < NLVL; ++l) {
        const float Nf = ns.nf[l];
        float t0 = x0 * Nf, t1 = x1 * Nf, t2 = x2 * Nf;
        float fl0 = floorf(t0), fl1 = floorf(t1), fl2 = floorf(t2);
        float p0 = t0 - fl0, p1 = t1 - fl1, p2 = t2 - fl2;
        unsigned m0 = (unsigned)fl0, m1 = (unsigned)fl1, m2 = (unsigned)fl2;
        unsigned a0 = m0,      a1 = m0 + 1u;
        unsigned b0 = m1 * P1, b1 = b0 + P1;
        unsigned c0 = m2 * P2, c1 = c0 + P2;
        float q0 = 1.0f - p0, q1 = 1.0f - p1, q2 = 1.0f - p2;
        float w00 = q0*q1, w01 = q0*p1, w10 = p0*q1, w11 = p0*p1;
        const float2* tl = tbl + l*TSIZE;
        float acc0 = 0.0f, acc1 = 0.0f;
#define GCORNER(A,B,C,WXY,WZ) { unsigned idx = ((A)^(B)^(C)) & (TSIZE-1); \
        float2 g = tl[idx]; float w = (WXY)*(WZ); \
        acc0 = fmaf(w, g.x, acc0); acc1 = fmaf(w, g.y, acc1); }
        GCORNER(a0, b0, c0, w00, q2)
        GCORNER(a0, b0, c1, w00, p2)
        GCORNER(a0, b1, c0, w01, q2)
        GCORNER(a0, b1, c1, w01, p2)
        GCORNER(a1, b0, c0, w10, q2)
        GCORNER(a1, b0, c1, w10, p2)
        GCORNER(a1, b1, c0, w11, q2)
        GCORNER(a1, b1, c1, w11, p2)
#undef GCORNER
        res[2*l]   = acc0;
        res[2*l+1] = acc1;
    }
    floatx4* o = (floatx4*)(out + (size_t)n * (2*NLVL));
    const floatx4* r = (const floatx4*)res;
#pragma unroll
    for (int j = 0; j < 8; ++j)
        o[j] = r[j];
}

extern "C" void kernel_launch(void* const* d_in, const int* in_sizes, int n_in,
                              void* d_out, int out_size, void* d_ws, size_t ws_size,
                              hipStream_t stream) {
    const float*  inp = (const float*)d_in[0];
    const float2* tbl = (const float2*)d_in[1];
    float* out = (float*)d_out;

    // Reproduce NS = [int(16 * b**i)] with host libm (values sit ~1e-14 from
    // exact powers of 2 at i=3,6,9,12,15 — must truncate identically).
    NsArg ns;
    double b = exp((log(512.0) - log(16.0)) / 15.0);
    for (int i = 0; i < NLVL; ++i)
        ns.nf[i] = (float)(int)(16.0 * pow(b, (double)i));

    int npts = in_sizes[0] / 3;

    size_t need = (size_t)NLVL * TSIZE * sizeof(__half2);   // 1 MiB
    if (ws_size >= need) {
        __half2* tblh = (__half2*)d_ws;
        int nt = NLVL * TSIZE;
        cvt_tbl<<<dim3((nt + 255) / 256), dim3(256), 0, stream>>>(tbl, tblh, nt);
        int blocks = (npts + PPB - 1) / PPB;
        hashgrid_pipe<<<dim3(blocks), dim3(BLK), 0, stream>>>(inp, tblh, out, ns, npts);
    } else {
        int blocks = (npts + 255) / 256;
        hashgrid_glb<<<dim3(blocks), dim3(256), 0, stream>>>(inp, tbl, out, ns, npts);
    }
}

// Round 13
// 538.170 us; speedup vs baseline: 1.0008x; 1.0008x over previous
//
#include <hip/hip_runtime.h>
#include <hip/hip_fp16.h>
#include <math.h>

#define NLVL 16
#define TSIZE 16384
#define BLK 1024
#define PPT 2                 // points per thread
#define PPB (BLK * PPT)       // points per block

typedef float floatx4 __attribute__((ext_vector_type(4)));

struct NsArg { float nf[NLVL]; };

// ---- pre-pass: f32 table -> f16 (values |v|<=1e-4 -> abs err <=5e-8) ----
__global__ __launch_bounds__(256) void cvt_tbl(
    const float2* __restrict__ src, __half2* __restrict__ dst, int n)
{
    int i = blockIdx.x * 256 + threadIdx.x;
    if (i < n) { float2 v = src[i]; dst[i] = __floats2half2_rn(v.x, v.y); }
}

// Hash operands pre-shifted by 2 ((x^y)<<2 == (x<<2)^(y<<2)); buffer select
// folded into one OR. LDS read = ds_read_b32 of __half2.
#define CORNER(E, CK, W, BUF) { \
    unsigned off = ((((E)^(CK)) & 0xFFFCu) | (BUF)); \
    __half2 g = *(const __half2*)((const char*)sh + off); \
    float2 gf = __half22float2(g); float w = (W); \
    acc0 = fmaf(w, gf.x, acc0); acc1 = fmaf(w, gf.y, acc1); }

#define GATHER(p, lc, BUF) { \
    float t0 = X0[p]*Nf, t1 = X1[p]*Nf, t2 = X2[p]*Nf; \
    float fl0 = floorf(t0), fl1 = floorf(t1), fl2 = floorf(t2); \
    float p0 = t0-fl0, p1 = t1-fl1, p2 = t2-fl2; \
    unsigned A0 = ((unsigned)fl0) << 2, A1 = A0 + 4u; \
    unsigned B0 = ((unsigned)fl1) * P1s, B1 = B0 + P1s; \
    unsigned C0 = ((unsigned)fl2) * P2s, C1 = C0 + P2s; \
    unsigned e00 = A0^B0, e01 = A0^B1, e10 = A1^B0, e11 = A1^B1; \
    float q0 = 1.f-p0, q1 = 1.f-p1, q2 = 1.f-p2; \
    float w00 = q0*q1, w01 = q0*p1, w10 = p0*q1, w11 = p0*p1; \
    float acc0 = 0.f, acc1 = 0.f; \
    CORNER(e00, C0, w00*q2, BUF) CORNER(e00, C1, w00*p2, BUF) \
    CORNER(e01, C0, w01*q2, BUF) CORNER(e01, C1, w01*p2, BUF) \
    CORNER(e10, C0, w10*q2, BUF) CORNER(e10, C1, w10*p2, BUF) \
    CORNER(e11, C0, w11*q2, BUF) CORNER(e11, C1, w11*p2, BUF) \
    res[p][2*(lc)]   = acc0; \
    res[p][2*(lc)+1] = acc1; }

// R13: dbuf with ONE barrier/level, phases strictly ordered
// gather(cur) -> stage(next, tight unroll-2 loop) -> barrier.
// No register lives across the gather body (R12's spill trigger); staging
// loads overlap other waves' gathers (VMEM vs LDS pipes).
__global__ __launch_bounds__(BLK) void hashgrid_dbuf(
    const float* __restrict__ inp,
    const __half2* __restrict__ tbl,   // f16 table in d_ws
    float* __restrict__ out,
    NsArg ns, int npts)
{
    __shared__ __align__(16) __half2 sh[2][TSIZE];   // 2 x 64 KiB
    const unsigned P1s = 2654435761u * 4u, P2s = 805459861u * 4u;
    const int tid  = threadIdx.x;
    const int base = blockIdx.x * PPB;

    float X0[PPT], X1[PPT], X2[PPT];
#pragma unroll
    for (int p = 0; p < PPT; ++p) {
        int n = base + tid + p * BLK;
        int m = n < npts ? n : 0;
        X0[p] = (inp[3*m+0] + 3.0f) / 6.0f;
        X1[p] = (inp[3*m+1] + 3.0f) / 6.0f;
        X2[p] = (inp[3*m+2] + 3.0f) / 6.0f;
    }

    // Prologue: stage level 0 into buffer 0 (R9-proven tight loop).
    {
        const floatx4* src = (const floatx4*)tbl;
        floatx4* dst = (floatx4*)&sh[0][0];
#pragma unroll 2
        for (int k = 0; k < 4; ++k)
            dst[tid + k*BLK] = src[tid + k*BLK];
    }
    __syncthreads();

    for (int c = 0; c < NLVL/4; ++c) {     // runtime: keeps code compact
        float res[PPT][8];                 // static-indexed, 16 floats

#pragma unroll
        for (int lc = 0; lc < 4; ++lc) {
            const int lvl = c*4 + lc;
            const unsigned BUF = (lc & 1) ? 65536u : 0u;  // lvl parity == lc parity
            const float Nf = ns.nf[lvl];

            // ---- phase 1: gather both points from current buffer ----
            GATHER(0, lc, BUF)
            GATHER(1, lc, BUF)

            // ---- phase 2: stage next level into the other buffer ----
            if (lvl + 1 < NLVL) {
                const floatx4* src = (const floatx4*)(tbl + (lvl+1) * TSIZE);
                floatx4* dst = (floatx4*)((char*)sh + (BUF ^ 65536u));
#pragma unroll 2
                for (int k = 0; k < 4; ++k)
                    dst[tid + k*BLK] = src[tid + k*BLK];
            }

            __syncthreads();   // ONE barrier/level
        }

        // ---- store chunk c: 2 float4 per point (proven clean traffic) ----
#pragma unroll
        for (int p = 0; p < PPT; ++p) {
            int n = base + tid + p * BLK;
            if (n < npts) {
                floatx4* o = (floatx4*)(out + (size_t)n * (2*NLVL) + c * 8);
                const floatx4* r = (const floatx4*)res[p];
                o[0] = r[0];
                o[1] = r[1];
            }
        }
    }
}

// ---- fallback (f32 direct global gathers) if ws too small ----
__global__ __launch_bounds__(256) void hashgrid_glb(
    const float* __restrict__ inp,
    const float2* __restrict__ tbl,
    float* __restrict__ out,
    NsArg ns, int npts)
{
    int n = blockIdx.x * 256 + threadIdx.x;
    if (n >= npts) return;
    const unsigned P1 = 2654435761u, P2 = 805459861u;
    float x0 = (inp[3*n+0] + 3.0f) / 6.0f;
    float x1 = (inp[3*n+1] + 3.0f) / 6.0f;
    float x2 = (inp[3*n+2] + 3.0f) / 6.0f;
    float res[2*NLVL];
#pragma unroll
    for (int l = 0; l < NLVL; ++l) {
        const float Nf = ns.nf[l];
        float t0 = x0 * Nf, t1 = x1 * Nf, t2 = x2 * Nf;
        float fl0 = floorf(t0), fl1 = floorf(t1), fl2 = floorf(t2);
        float p0 = t0 - fl0, p1 = t1 - fl1, p2 = t2 - fl2;
        unsigned m0 = (unsigned)fl0, m1 = (unsigned)fl1, m2 = (unsigned)fl2;
        unsigned a0 = m0,      a1 = m0 + 1u;
        unsigned b0 = m1 * P1, b1 = b0 + P1;
        unsigned c0 = m2 * P2, c1 = c0 + P2;
        float q0 = 1.0f - p0, q1 = 1.0f - p1, q2 = 1.0f - p2;
        float w00 = q0*q1, w01 = q0*p1, w10 = p0*q1, w11 = p0*p1;
        const float2* tl = tbl + l*TSIZE;
        float acc0 = 0.0f, acc1 = 0.0f;
#define GCORNER(A,B,C,WXY,WZ) { unsigned idx = ((A)^(B)^(C)) & (TSIZE-1); \
        float2 g = tl[idx]; float w = (WXY)*(WZ); \
        acc0 = fmaf(w, g.x, acc0); acc1 = fmaf(w, g.y, acc1); }
        GCORNER(a0, b0, c0, w00, q2)
        GCORNER(a0, b0, c1, w00, p2)
        GCORNER(a0, b1, c0, w01, q2)
        GCORNER(a0, b1, c1, w01, p2)
        GCORNER(a1, b0, c0, w10, q2)
        GCORNER(a1, b0, c1, w10, p2)
        GCORNER(a1, b1, c0, w11, q2)
        GCORNER(a1, b1, c1, w11, p2)
#undef GCORNER
        res[2*l]   = acc0;
        res[2*l+1] = acc1;
    }
    floatx4* o = (floatx4*)(out + (size_t)n * (2*NLVL));
    const floatx4* r = (const floatx4*)res;
#pragma unroll
    for (int j = 0; j < 8; ++j)
        o[j] = r[j];
}

extern "C" void kernel_launch(void* const* d_in, const int* in_sizes, int n_in,
                              void* d_out, int out_size, void* d_ws, size_t ws_size,
                              hipStream_t stream) {
    const float*  inp = (const float*)d_in[0];
    const float2* tbl = (const float2*)d_in[1];
    float* out = (float*)d_out;

    // Reproduce NS = [int(16 * b**i)] with host libm (values sit ~1e-14 from
    // exact powers of 2 at i=3,6,9,12,15 — must truncate identically).
    NsArg ns;
    double b = exp((log(512.0) - log(16.0)) / 15.0);
    for (int i = 0; i < NLVL; ++i)
        ns.nf[i] = (float)(int)(16.0 * pow(b, (double)i));

    int npts = in_sizes[0] / 3;

    size_t need = (size_t)NLVL * TSIZE * sizeof(__half2);   // 1 MiB
    if (ws_size >= need) {
        __half2* tblh = (__half2*)d_ws;
        int nt = NLVL * TSIZE;
        cvt_tbl<<<dim3((nt + 255) / 256), dim3(256), 0, stream>>>(tbl, tblh, nt);
        int blocks = (npts + PPB - 1) / PPB;
        hashgrid_dbuf<<<dim3(blocks), dim3(BLK), 0, stream>>>(inp, tblh, out, ns, npts);
    } else {
        int blocks = (npts + 255) / 256;
        hashgrid_glb<<<dim3(blocks), dim3(256), 0, stream>>>(inp, tbl, out, ns, npts);
    }
}

// Round 14
// 324.793 us; speedup vs baseline: 1.6583x; 1.6570x over previous
//
#include <hip/hip_runtime.h>
#include <hip/hip_fp16.h>
#include <math.h>

#define NLVL 16
#define TSIZE 16384
#define BLK 512               // 64KB LDS caps at 2 blocks/CU -> VGPR<=128 free
#define PPT 3                 // R14: 3 points/thread (res 24 floats, ~70 live)
#define PPB (BLK * PPT)       // 1536 points per block
#define LPC 4                 // levels per output chunk
#define NCHUNK (NLVL / LPC)

typedef float floatx4 __attribute__((ext_vector_type(4)));

struct NsArg { float nf[NLVL]; };

// ---- pre-pass: f32 table -> f16 (values |v|<=1e-4 -> abs err <=5e-8) ----
__global__ __launch_bounds__(256) void cvt_tbl(
    const float2* __restrict__ src, __half2* __restrict__ dst, int n)
{
    int i = blockIdx.x * 256 + threadIdx.x;
    if (i < n) { float2 v = src[i]; dst[i] = __floats2half2_rn(v.x, v.y); }
}

// R9/R11-proven shape ONLY: single 64KB buffer, sh[idx] element addressing,
// tight staging loop, stage/gather strictly separated. All dbuf / flat-byte /
// pre-shifted-prime variants spilled (R12,R13); global_load_lds dbuf added
// +0.7GB HBM (R7,R10). Deltas vs R11: PPT 2->3 (1.5x fewer barrier+staging
// events per point), staging unroll 2->4 (halves exposed L2 waits).
__global__ __launch_bounds__(BLK) void hashgrid_f16(
    const float* __restrict__ inp,
    const __half2* __restrict__ tbl,   // f16 table in d_ws
    float* __restrict__ out,
    NsArg ns, int npts)
{
    __shared__ __align__(16) __half2 sh[TSIZE];   // 64 KiB: one level
    const unsigned P1 = 2654435761u, P2 = 805459861u;
    const int tid = threadIdx.x;
    const int base = blockIdx.x * PPB;

    float X0[PPT], X1[PPT], X2[PPT];
#pragma unroll
    for (int p = 0; p < PPT; ++p) {
        int n = base + tid + p * BLK;
        int m = n < npts ? n : 0;
        X0[p] = (inp[3*m+0] + 3.0f) / 6.0f;
        X1[p] = (inp[3*m+1] + 3.0f) / 6.0f;
        X2[p] = (inp[3*m+2] + 3.0f) / 6.0f;
    }

#pragma unroll
    for (int c = 0; c < NCHUNK; ++c) {
        float res[PPT][2*LPC];            // 24 floats live

#pragma unroll
        for (int lc = 0; lc < LPC; ++lc) {
            const int l = c * LPC + lc;
            // ---- stage level-l f16 table (64KB); unroll 4 = 2 exposed
            //      L2 round-trips (16 staging regs, occupancy-free at BLK=512)
            {
                const floatx4* src = (const floatx4*)(tbl + l * TSIZE);
                floatx4* dst = (floatx4*)sh;
#pragma unroll 4
                for (int k = 0; k < TSIZE/4/BLK; ++k)   // 8 iters, 16B/lane
                    dst[tid + k*BLK] = src[tid + k*BLK];
            }
            __syncthreads();

            const float Nf = ns.nf[l];
#pragma unroll
            for (int p = 0; p < PPT; ++p) {
                float t0 = X0[p] * Nf, t1 = X1[p] * Nf, t2 = X2[p] * Nf;
                float fl0 = floorf(t0), fl1 = floorf(t1), fl2 = floorf(t2);
                float p0 = t0 - fl0, p1 = t1 - fl1, p2 = t2 - fl2;
                unsigned m0 = (unsigned)fl0, m1 = (unsigned)fl1, m2 = (unsigned)fl2;
                unsigned a0 = m0,      a1 = m0 + 1u;
                unsigned b0 = m1 * P1, b1 = b0 + P1;
                unsigned c0 = m2 * P2, c1 = c0 + P2;
                float q0 = 1.0f - p0, q1 = 1.0f - p1, q2 = 1.0f - p2;
                float w00 = q0*q1, w01 = q0*p1, w10 = p0*q1, w11 = p0*p1;
                float acc0 = 0.0f, acc1 = 0.0f;
#define CORNER(A,B,C,WXY,WZ) { unsigned idx = ((A)^(B)^(C)) & (TSIZE-1); \
                float2 g = __half22float2(sh[idx]); float w = (WXY)*(WZ); \
                acc0 = fmaf(w, g.x, acc0); acc1 = fmaf(w, g.y, acc1); }
                CORNER(a0, b0, c0, w00, q2)
                CORNER(a0, b0, c1, w00, p2)
                CORNER(a0, b1, c0, w01, q2)
                CORNER(a0, b1, c1, w01, p2)
                CORNER(a1, b0, c0, w10, q2)
                CORNER(a1, b0, c1, w10, p2)
                CORNER(a1, b1, c0, w11, q2)
                CORNER(a1, b1, c1, w11, p2)
#undef CORNER
                res[p][2*lc]   = acc0;
                res[p][2*lc+1] = acc1;
            }
            __syncthreads();   // protect LDS before next level's staging
        }

        // ---- store this chunk: 2 float4 per point (proven clean traffic) ----
#pragma unroll
        for (int p = 0; p < PPT; ++p) {
            int n = base + tid + p * BLK;
            if (n < npts) {
                floatx4* o = (floatx4*)(out + (size_t)n * (2*NLVL) + c * (2*LPC));
                const floatx4* r = (const floatx4*)res[p];
                o[0] = r[0];
                o[1] = r[1];
            }
        }
    }
}

// ---- fallback (f32 direct global gathers) if ws too small ----
__global__ __launch_bounds__(256) void hashgrid_glb(
    const float* __restrict__ inp,
    const float2* __restrict__ tbl,
    float* __restrict__ out,
    NsArg ns, int npts)
{
    int n = blockIdx.x * 256 + threadIdx.x;
    if (n >= npts) return;
    const unsigned P1 = 2654435761u, P2 = 805459861u;
    float x0 = (inp[3*n+0] + 3.0f) / 6.0f;
    float x1 = (inp[3*n+1] + 3.0f) / 6.0f;
    float x2 = (inp[3*n+2] + 3.0f) / 6.0f;
    float res[2*NLVL];
#pragma unroll
    for (int l = 0; l < NLVL; ++l) {
        const float Nf = ns.nf[l];
        float t0 = x0 * Nf, t1 = x1 * Nf, t2 = x2 * Nf;
        float fl0 = floorf(t0), fl1 = floorf(t1), fl2 = floorf(t2);
        float p0 = t0 - fl0, p1 = t1 - fl1, p2 = t2 - fl2;
        unsigned m0 = (unsigned)fl0, m1 = (unsigned)fl1, m2 = (unsigned)fl2;
        unsigned a0 = m0,      a1 = m0 + 1u;
        unsigned b0 = m1 * P1, b1 = b0 + P1;
        unsigned c0 = m2 * P2, c1 = c0 + P2;
        float q0 = 1.0f - p0, q1 = 1.0f - p1, q2 = 1.0f - p2;
        float w00 = q0*q1, w01 = q0*p1, w10 = p0*q1, w11 = p0*p1;
        const float2* tl = tbl + l*TSIZE;
        float acc0 = 0.0f, acc1 = 0.0f;
#define GCORNER(A,B,C,WXY,WZ) { unsigned idx = ((A)^(B)^(C)) & (TSIZE-1); \
        float2 g = tl[idx]; float w = (WXY)*(WZ); \
        acc0 = fmaf(w, g.x, acc0); acc1 = fmaf(w, g.y, acc1); }
        GCORNER(a0, b0, c0, w00, q2)
        GCORNER(a0, b0, c1, w00, p2)
        GCORNER(a0, b1, c0, w01, q2)
        GCORNER(a0, b1, c1, w01, p2)
        GCORNER(a1, b0, c0, w10, q2)
        GCORNER(a1, b0, c1, w10, p2)
        GCORNER(a1, b1, c0, w11, q2)
        GCORNER(a1, b1, c1, w11, p2)
#undef GCORNER
        res[2*l]   = acc0;
        res[2*l+1] = acc1;
    }
    floatx4* o = (floatx4*)(out + (size_t)n * (2*NLVL));
    const floatx4* r = (const floatx4*)res;
#pragma unroll
    for (int j = 0; j < 8; ++j)
        o[j] = r[j];
}

extern "C" void kernel_launch(void* const* d_in, const int* in_sizes, int n_in,
                              void* d_out, int out_size, void* d_ws, size_t ws_size,
                              hipStream_t stream) {
    const float*  inp = (const float*)d_in[0];
    const float2* tbl = (const float2*)d_in[1];
    float* out = (float*)d_out;

    // Reproduce NS = [int(16 * b**i)] with host libm (values sit ~1e-14 from
    // exact powers of 2 at i=3,6,9,12,15 — must truncate identically).
    NsArg ns;
    double b = exp((log(512.0) - log(16.0)) / 15.0);
    for (int i = 0; i < NLVL; ++i)
        ns.nf[i] = (float)(int)(16.0 * pow(b, (double)i));

    int npts = in_sizes[0] / 3;

    size_t need = (size_t)NLVL * TSIZE * sizeof(__half2);   // 1 MiB
    if (ws_size >= need) {
        __half2* tblh = (__half2*)d_ws;
        int nt = NLVL * TSIZE;
        cvt_tbl<<<dim3((nt + 255) / 256), dim3(256), 0, stream>>>(tbl, tblh, nt);
        int blocks = (npts + PPB - 1) / PPB;
        hashgrid_f16<<<dim3(blocks), dim3(BLK), 0, stream>>>(inp, tblh, out, ns, npts);
    } else {
        int blocks = (npts + 255) / 256;
        hashgrid_glb<<<dim3(blocks), dim3(256), 0, stream>>>(inp, tbl, out, ns, npts);
    }
}

// Round 15
// 251.335 us; speedup vs baseline: 2.1430x; 1.2923x over previous
//
#include <hip/hip_runtime.h>
#include <hip/hip_fp16.h>
#include <math.h>

#define NLVL 16
#define TSIZE 16384
#define BLK 512               // 2 blocks/CU (LDS 64KB each) iff VGPR<=64
#define PPT 2                 // points per thread (res 16 floats — the wall)
#define PPB (BLK * PPT)       // points per block
#define LPC 4                 // levels per output chunk
#define NCHUNK (NLVL / LPC)

typedef float floatx4 __attribute__((ext_vector_type(4)));

struct NsArg { float nf[NLVL]; };

// ---- pre-pass: f32 table -> f16 (values |v|<=1e-4 -> abs err <=5e-8) ----
__global__ __launch_bounds__(256) void cvt_tbl(
    const float2* __restrict__ src, __half2* __restrict__ dst, int n)
{
    int i = blockIdx.x * 256 + threadIdx.x;
    if (i < n) { float2 v = src[i]; dst[i] = __floats2half2_rn(v.x, v.y); }
}

// R11 structure EXACTLY (proven clean: 39MB/267MB, VGPR 60, 249us).
// R15 delta: address-math diet only. Hash operands pre-shifted by 2
// ((x^y)<<2 == (x<<2)^(y<<2)), so corner LDS BYTE offset = (e^C)&0xFFFC:
// 2 int ops/corner vs 4. All level indices stay COMPILE-TIME (runtime
// ns.nf[lvl] indexing was the R12/R13 scratch-spill trigger).
__global__ __launch_bounds__(BLK) void hashgrid_f16(
    const float* __restrict__ inp,
    const __half2* __restrict__ tbl,   // f16 table in d_ws
    float* __restrict__ out,
    NsArg ns, int npts)
{
    __shared__ __align__(16) __half2 sh[TSIZE];   // 64 KiB: one level
    const unsigned P1s = 2654435761u * 4u, P2s = 805459861u * 4u;
    const int tid = threadIdx.x;
    const int base = blockIdx.x * PPB;
    const char* shb = (const char*)sh;

    float X0[PPT], X1[PPT], X2[PPT];
#pragma unroll
    for (int p = 0; p < PPT; ++p) {
        int n = base + tid + p * BLK;
        int m = n < npts ? n : 0;
        X0[p] = (inp[3*m+0] + 3.0f) / 6.0f;
        X1[p] = (inp[3*m+1] + 3.0f) / 6.0f;
        X2[p] = (inp[3*m+2] + 3.0f) / 6.0f;
    }

#pragma unroll
    for (int c = 0; c < NCHUNK; ++c) {
        float res[PPT][2*LPC];            // 16 floats live

#pragma unroll
        for (int lc = 0; lc < LPC; ++lc) {
            const int l = c * LPC + lc;   // compile-time
            // ---- stage level-l f16 table (64KB); unroll 2 keeps only
            //      8 data regs in flight (R6/R9/R11-proven spill-free) ----
            {
                const floatx4* src = (const floatx4*)(tbl + l * TSIZE);
                floatx4* dst = (floatx4*)sh;
#pragma unroll 2
                for (int k = 0; k < TSIZE/4/BLK; ++k)   // 8 iters, 16B/lane
                    dst[tid + k*BLK] = src[tid + k*BLK];
            }
            __syncthreads();

            const float Nf = ns.nf[l];
#pragma unroll
            for (int p = 0; p < PPT; ++p) {
                float t0 = X0[p] * Nf, t1 = X1[p] * Nf, t2 = X2[p] * Nf;
                float fl0 = floorf(t0), fl1 = floorf(t1), fl2 = floorf(t2);
                float p0 = t0 - fl0, p1 = t1 - fl1, p2 = t2 - fl2;
                unsigned A0 = ((unsigned)fl0) << 2, A1 = A0 + 4u;
                unsigned B0 = ((unsigned)fl1) * P1s, B1 = B0 + P1s;
                unsigned C0 = ((unsigned)fl2) * P2s, C1 = C0 + P2s;
                unsigned e00 = A0^B0, e01 = A0^B1, e10 = A1^B0, e11 = A1^B1;
                float q0 = 1.0f - p0, q1 = 1.0f - p1, q2 = 1.0f - p2;
                float w00 = q0*q1, w01 = q0*p1, w10 = p0*q1, w11 = p0*p1;
                float acc0 = 0.0f, acc1 = 0.0f;
#define CORNER(E, CK, W) { unsigned off = ((E)^(CK)) & 0xFFFCu; \
                __half2 g = *(const __half2*)(shb + off); \
                float2 gf = __half22float2(g); float w = (W); \
                acc0 = fmaf(w, gf.x, acc0); acc1 = fmaf(w, gf.y, acc1); }
                CORNER(e00, C0, w00*q2)
                CORNER(e00, C1, w00*p2)
                CORNER(e01, C0, w01*q2)
                CORNER(e01, C1, w01*p2)
                CORNER(e10, C0, w10*q2)
                CORNER(e10, C1, w10*p2)
                CORNER(e11, C0, w11*q2)
                CORNER(e11, C1, w11*p2)
#undef CORNER
                res[p][2*lc]   = acc0;
                res[p][2*lc+1] = acc1;
            }
            __syncthreads();   // protect LDS before next level's staging
        }

        // ---- store this chunk: 2 float4 per point (proven clean traffic) ----
#pragma unroll
        for (int p = 0; p < PPT; ++p) {
            int n = base + tid + p * BLK;
            if (n < npts) {
                floatx4* o = (floatx4*)(out + (size_t)n * (2*NLVL) + c * (2*LPC));
                const floatx4* r = (const floatx4*)res[p];
                o[0] = r[0];
                o[1] = r[1];
            }
        }
    }
}

// ---- fallback (f32 direct global gathers) if ws too small ----
__global__ __launch_bounds__(256) void hashgrid_glb(
    const float* __restrict__ inp,
    const float2* __restrict__ tbl,
    float* __restrict__ out,
    NsArg ns, int npts)
{
    int n = blockIdx.x * 256 + threadIdx.x;
    if (n >= npts) return;
    const unsigned P1 = 2654435761u, P2 = 805459861u;
    float x0 = (inp[3*n+0] + 3.0f) / 6.0f;
    float x1 = (inp[3*n+1] + 3.0f) / 6.0f;
    float x2 = (inp[3*n+2] + 3.0f) / 6.0f;
    float res[2*NLVL];
#pragma unroll
    for (int l = 0; l < NLVL; ++l) {
        const float Nf = ns.nf[l];
        float t0 = x0 * Nf, t1 = x1 * Nf, t2 = x2 * Nf;
        float fl0 = floorf(t0), fl1 = floorf(t1), fl2 = floorf(t2);
        float p0 = t0 - fl0, p1 = t1 - fl1, p2 = t2 - fl2;
        unsigned m0 = (unsigned)fl0, m1 = (unsigned)fl1, m2 = (unsigned)fl2;
        unsigned a0 = m0,      a1 = m0 + 1u;
        unsigned b0 = m1 * P1, b1 = b0 + P1;
        unsigned c0 = m2 * P2, c1 = c0 + P2;
        float q0 = 1.0f - p0, q1 = 1.0f - p1, q2 = 1.0f - p2;
        float w00 = q0*q1, w01 = q0*p1, w10 = p0*q1, w11 = p0*p1;
        const float2* tl = tbl + l*TSIZE;
        float acc0 = 0.0f, acc1 = 0.0f;
#define GCORNER(A,B,C,WXY,WZ) { unsigned idx = ((A)^(B)^(C)) & (TSIZE-1); \
        float2 g = tl[idx]; float w = (WXY)*(WZ); \
        acc0 = fmaf(w, g.x, acc0); acc1 = fmaf(w, g.y, acc1); }
        GCORNER(a0, b0, c0, w00, q2)
        GCORNER(a0, b0, c1, w00, p2)
        GCORNER(a0, b1, c0, w01, q2)
        GCORNER(a0, b1, c1, w01, p2)
        GCORNER(a1, b0, c0, w10, q2)
        GCORNER(a1, b0, c1, w10, p2)
        GCORNER(a1, b1, c0, w11, q2)
        GCORNER(a1, b1, c1, w11, p2)
#undef GCORNER
        res[2*l]   = acc0;
        res[2*l+1] = acc1;
    }
    floatx4* o = (floatx4*)(out + (size_t)n * (2*NLVL));
    const floatx4* r = (const floatx4*)res;
#pragma unroll
    for (int j = 0; j < 8; ++j)
        o[j] = r[j];
}

extern "C" void kernel_launch(void* const* d_in, const int* in_sizes, int n_in,
                              void* d_out, int out_size, void* d_ws, size_t ws_size,
                              hipStream_t stream) {
    const float*  inp = (const float*)d_in[0];
    const float2* tbl = (const float2*)d_in[1];
    float* out = (float*)d_out;

    // Reproduce NS = [int(16 * b**i)] with host libm (values sit ~1e-14 from
    // exact powers of 2 at i=3,6,9,12,15 — must truncate identically).
    NsArg ns;
    double b = exp((log(512.0) - log(16.0)) / 15.0);
    for (int i = 0; i < NLVL; ++i)
        ns.nf[i] = (float)(int)(16.0 * pow(b, (double)i));

    int npts = in_sizes[0] / 3;

    size_t need = (size_t)NLVL * TSIZE * sizeof(__half2);   // 1 MiB
    if (ws_size >= need) {
        __half2* tblh = (__half2*)d_ws;
        int nt = NLVL * TSIZE;
        cvt_tbl<<<dim3((nt + 255) / 256), dim3(256), 0, stream>>>(tbl, tblh, nt);
        int blocks = (npts + PPB - 1) / PPB;
        hashgrid_f16<<<dim3(blocks), dim3(BLK), 0, stream>>>(inp, tblh, out, ns, npts);
    } else {
        int blocks = (npts + 255) / 256;
        hashgrid_glb<<<dim3(blocks), dim3(256), 0, stream>>>(inp, tbl, out, ns, npts);
    }
}